// Round 4
// baseline (166.800 us; speedup 1.0000x reference)
//
#include <hip/hip_runtime.h>

// B=8, IN=256, HEADS=8, KEY=64, MEM=64, HEAD_DIM=64, OUT=256, HW=4096
// Single-kernel folded form:
//   phase F (distributed fold):
//     A[(n,m)][c]  = sum_k key_p[n][k][m] * w_in[k*8+n][c]     (+ bb from b_in)
//     M[o][(n,m)]  = sum_d w_out[o][n*64+d] * memory[n][m][d]
//   phase G: logits = A @ x + bb  -> softmax(64-row groups) -> out = M @ probs + b_out
// 512 blocks == exactly 2 blocks/CU (64 KB LDS, launch_bounds(256,2)) -> co-resident,
// software grid handshake via per-block flags in d_ws (idempotent MAGIC writes).

typedef _Float16 half8 __attribute__((ext_vector_type(8)));
typedef _Float16 half4 __attribute__((ext_vector_type(4)));
typedef _Float16 half2v __attribute__((ext_vector_type(2)));
typedef float float4v __attribute__((ext_vector_type(4)));

#define MAGIC 0x5A17F00Du
#define XS_STRIDE 264

__global__ __launch_bounds__(256, 2) void fused_all(
    const float* __restrict__ x, const float* __restrict__ key_p,
    const float* __restrict__ memory, const float* __restrict__ w_in,
    const float* __restrict__ b_in, const float* __restrict__ w_out,
    const float* __restrict__ b_out,
    _Float16* __restrict__ Aswz, _Float16* __restrict__ Mswz,
    float* __restrict__ bb, unsigned int* __restrict__ flags,
    float* __restrict__ out)
{
    __shared__ _Float16 S[32768];   // 64 KB; phase F uses first 512 B as float scratch

    const int t  = threadIdx.x;
    const int w  = t >> 6;          // wave 0..3
    const int l  = t & 63;          // lane
    const int q  = l >> 4;          // quadrant 0..3
    const int lp = l & 15;
    const int wg  = blockIdx.x;     // 0..511
    const int b   = wg >> 6;
    const int hw0 = (wg & 63) * 64;
    const float* xb = x + (size_t)b * 256 * 4096 + hw0;

    float* svf = (float*)S;         // [0..63] key column, [64..127] bias partials

    // ================= phase F: fold =================
    {
        const int row = wg, n = row >> 6, m = row & 63;
        if (t < 64) svf[t] = key_p[n * 4096 + t * 64 + m];
        __syncthreads();
        if (t < 64) svf[64 + t] = svf[t] * b_in[t * 8 + n];
        // A-row: c = t
        float v = 0.f;
        #pragma unroll 16
        for (int k = 0; k < 64; ++k)
            v = fmaf(svf[k], w_in[(k * 8 + n) * 256 + t], v);
        {
            int R = row >> 4, s = t >> 5, i = t & 7;
            int lq = (row & 15) + 16 * ((t >> 3) & 3);
            Aswz[(((R * 8 + s) * 64 + lq) << 3) + i] = (_Float16)v;
        }
        // M-row for blocks 0..255: o = wg, cols t and t+256
        if (wg < 256) {
            const int o = wg;
            #pragma unroll
            for (int hh = 0; hh < 2; ++hh) {
                int col = t + hh * 256, nn = col >> 6, mm = col & 63;
                const float4* mrow = (const float4*)(memory + nn * 4096 + mm * 64);
                const float4* wrow = (const float4*)(w_out + o * 512 + nn * 64);
                float mv = 0.f;
                #pragma unroll
                for (int qd = 0; qd < 16; ++qd) {
                    float4 a = mrow[qd], ww = wrow[qd];
                    mv += a.x * ww.x + a.y * ww.y + a.z * ww.z + a.w * ww.w;
                }
                int R2 = o >> 4, s = col >> 5, i = col & 7;
                int lq = (o & 15) + 16 * ((col >> 3) & 3);
                Mswz[(((R2 * 16 + s) * 64 + lq) << 3) + i] = (_Float16)mv;
            }
        }
        __syncthreads();   // all fold global writes issued+done; svf reads done
        if (t == 0) {
            float s2 = 0.f;
            #pragma unroll
            for (int k = 0; k < 64; ++k) s2 += svf[64 + k];
            bb[row] = s2;
            __threadfence();   // agent-scope: push Aswz/Mswz/bb toward coherent point
            __hip_atomic_store(&flags[wg], MAGIC, __ATOMIC_RELAXED, __HIP_MEMORY_SCOPE_AGENT);
        }
        __syncthreads();   // svf region free before x staging overwrites it
    }

    // ================= stage Xs[p][c] fp16 (overlaps other blocks' folds) =================
    #pragma unroll
    for (int i = 0; i < 8; ++i) {
        int u  = i * 256 + t;
        int cp = u & 127;           // channel pair
        int qq = u >> 7;            // position quad 0..15
        int c0 = cp * 2, p4 = qq * 4;
        const float* px = xb + (size_t)c0 * 4096 + p4;
        float4 v0 = *(const float4*)(px);
        float4 v1 = *(const float4*)(px + 4096);
        *(half2v*)(&S[(p4 + 0) * XS_STRIDE + c0]) = half2v{(_Float16)v0.x, (_Float16)v1.x};
        *(half2v*)(&S[(p4 + 1) * XS_STRIDE + c0]) = half2v{(_Float16)v0.y, (_Float16)v1.y};
        *(half2v*)(&S[(p4 + 2) * XS_STRIDE + c0]) = half2v{(_Float16)v0.z, (_Float16)v1.z};
        *(half2v*)(&S[(p4 + 3) * XS_STRIDE + c0]) = half2v{(_Float16)v0.w, (_Float16)v1.w};
    }

    // ================= grid handshake: wait for all 512 fold producers =================
    {
        #pragma unroll
        for (int f = 0; f < 2; ++f) {
            const unsigned int* fp = flags + t + f * 256;
            while (__hip_atomic_load(fp, __ATOMIC_RELAXED, __HIP_MEMORY_SCOPE_AGENT) != MAGIC)
                __builtin_amdgcn_s_sleep(8);
        }
        __threadfence();   // acquire: invalidate stale cached A/M before reading
    }
    __syncthreads();       // staging complete + all threads past handshake

    // ================= GEMM1: logits[512 x 64] =================
    float4v acc[8][4];
    #pragma unroll
    for (int r = 0; r < 8; ++r)
        #pragma unroll
        for (int c = 0; c < 4; ++c) acc[r][c] = float4v{0.f, 0.f, 0.f, 0.f};

    const half8* Ag = (const half8*)Aswz;
    for (int s = 0; s < 8; ++s) {
        half8 bf[4];
        #pragma unroll
        for (int c = 0; c < 4; ++c)
            bf[c] = *(const half8*)(&S[(c * 16 + lp) * XS_STRIDE + s * 32 + q * 8]);
        half8 af[8];
        #pragma unroll
        for (int r = 0; r < 8; ++r)
            af[r] = Ag[((w * 8 + r) * 8 + s) * 64 + l];
        #pragma unroll
        for (int r = 0; r < 8; ++r)
            #pragma unroll
            for (int c = 0; c < 4; ++c)
                acc[r][c] = __builtin_amdgcn_mfma_f32_16x16x32_f16(af[r], bf[c], acc[r][c], 0, 0, 0);
    }

    // ---- bias ----
    #pragma unroll
    for (int r = 0; r < 8; ++r) {
        float4v bbv = *(const float4v*)(bb + w * 128 + r * 16 + q * 4);
        #pragma unroll
        for (int c = 0; c < 4; ++c)
            #pragma unroll
            for (int j = 0; j < 4; ++j) acc[r][c][j] += bbv[j];
    }

    __syncthreads();   // all waves done reading Xs (P region aliases it)

    // ---- softmax + store P in B-fragment layout ----
    #pragma unroll
    for (int h = 0; h < 2; ++h) {
        #pragma unroll
        for (int c = 0; c < 4; ++c) {
            float mx = -1e30f;
            #pragma unroll
            for (int rr = 0; rr < 4; ++rr) {
                int r = h * 4 + rr;
                #pragma unroll
                for (int j = 0; j < 4; ++j) mx = fmaxf(mx, acc[r][c][j]);
            }
            mx = fmaxf(mx, __shfl_xor(mx, 16, 64));
            mx = fmaxf(mx, __shfl_xor(mx, 32, 64));
            float sum = 0.f;
            #pragma unroll
            for (int rr = 0; rr < 4; ++rr) {
                int r = h * 4 + rr;
                #pragma unroll
                for (int j = 0; j < 4; ++j) {
                    float e = __expf(acc[r][c][j] - mx);
                    acc[r][c][j] = e;
                    sum += e;
                }
            }
            sum += __shfl_xor(sum, 16, 64);
            sum += __shfl_xor(sum, 32, 64);
            float inv = 1.f / sum;
            #pragma unroll
            for (int rr = 0; rr < 4; ++rr) {
                int r = h * 4 + rr;
                int s2 = w * 4 + (r >> 1);
                int lq = ((r & 1) * 2 + (q >> 1)) * 16 + lp;
                int i0 = (q & 1) * 4;
                half4 pv = {(_Float16)(acc[r][c][0] * inv), (_Float16)(acc[r][c][1] * inv),
                            (_Float16)(acc[r][c][2] * inv), (_Float16)(acc[r][c][3] * inv)};
                *(half4*)(&S[(((s2 * 4 + c) * 64) + lq) * 8 + i0]) = pv;
            }
        }
    }
    __syncthreads();

    // ================= GEMM2: out[256 x 64] = M[256x512] @ P =================
    float4v acc2[4][4];
    #pragma unroll
    for (int r = 0; r < 4; ++r)
        #pragma unroll
        for (int c = 0; c < 4; ++c) acc2[r][c] = float4v{0.f, 0.f, 0.f, 0.f};

    const half8* Mg = (const half8*)Mswz;
    for (int s2 = 0; s2 < 16; ++s2) {
        half8 bf2[4];
        #pragma unroll
        for (int c = 0; c < 4; ++c)
            bf2[c] = *(const half8*)(&S[(((s2 * 4 + c) * 64) + l) * 8]);   // conflict-free b128
        half8 af2[4];
        #pragma unroll
        for (int r = 0; r < 4; ++r)
            af2[r] = Mg[((w * 4 + r) * 16 + s2) * 64 + l];
        #pragma unroll
        for (int r = 0; r < 4; ++r)
            #pragma unroll
            for (int c = 0; c < 4; ++c)
                acc2[r][c] = __builtin_amdgcn_mfma_f32_16x16x32_f16(af2[r], bf2[c], acc2[r][c], 0, 0, 0);
    }

    // ---- epilogue ----
    #pragma unroll
    for (int r = 0; r < 4; ++r) {
        int ob = w * 64 + r * 16 + q * 4;
        float4v bo = *(const float4v*)(b_out + ob);
        #pragma unroll
        for (int j = 0; j < 4; ++j) {
            float* orow = out + ((size_t)b * 256 + ob + j) * 4096 + hw0;
            #pragma unroll
            for (int c = 0; c < 4; ++c)
                orow[c * 16 + lp] = acc2[r][c][j] + bo[j];
        }
    }
}

extern "C" void kernel_launch(void* const* d_in, const int* in_sizes, int n_in,
                              void* d_out, int out_size, void* d_ws, size_t ws_size,
                              hipStream_t stream) {
    (void)in_sizes; (void)n_in; (void)ws_size; (void)out_size;
    const float* x      = (const float*)d_in[0];
    const float* key_p  = (const float*)d_in[1];
    const float* memory = (const float*)d_in[2];
    const float* w_in   = (const float*)d_in[3];
    const float* b_in   = (const float*)d_in[4];
    const float* w_out  = (const float*)d_in[5];
    const float* b_out  = (const float*)d_in[6];
    float* out = (float*)d_out;

    _Float16*     Aswz  = (_Float16*)d_ws;                   // 512*256 fp16 = 256 KB
    _Float16*     Mswz  = Aswz + 512 * 256;                  // 256*512 fp16 = 256 KB
    float*        bb    = (float*)(Mswz + 256 * 512);        // 512 fp32 = 2 KB
    unsigned int* flags = (unsigned int*)(bb + 512);         // 512 u32  = 2 KB

    fused_all<<<512, 256, 0, stream>>>(x, key_p, memory, w_in, b_in, w_out, b_out,
                                       Aswz, Mswz, bb, flags, out);
}

// Round 5
// 129.608 us; speedup vs baseline: 1.2870x; 1.2870x over previous
//
#include <hip/hip_runtime.h>

// B=8, IN=256, HEADS=8, KEY=64, MEM=64, HEAD_DIM=64, OUT=256, HW=4096
// Folded form (two kernels; kernel boundary provides fold->main coherence + L2 reset):
//   A[(n,m)][c]  = sum_k key_p[n][k][m] * w_in[k*8+n][c]   (+ bb from b_in)
//   M[o][(n,m)]  = sum_d w_out[o][n*64+d] * memory[n][m][d]
//   logits = A @ x + bb -> softmax(64-row groups) -> out = M @ probs + b_out

typedef _Float16 half8 __attribute__((ext_vector_type(8)));
typedef _Float16 half4 __attribute__((ext_vector_type(4)));
typedef _Float16 half2v __attribute__((ext_vector_type(2)));
typedef float float4v __attribute__((ext_vector_type(4)));

// ---------------- merged fold kernel ----------------
// blocks 0..511: A row (n*64+m); blocks 512..767: M row (o)
__global__ __launch_bounds__(256) void fold_all(
    const float* __restrict__ key_p, const float* __restrict__ w_in,
    const float* __restrict__ b_in, const float* __restrict__ w_out,
    const float* __restrict__ memory,
    _Float16* __restrict__ Aswz, _Float16* __restrict__ Mswz, float* __restrict__ bb)
{
    __shared__ float sv[512];
    __shared__ float red[64];
    const int blk = blockIdx.x;
    const int t = threadIdx.x;

    if (blk < 512) {
        const int row = blk, n = row >> 6, m = row & 63;
        if (t < 64) sv[t] = key_p[n * 4096 + t * 64 + m];   // key column
        __syncthreads();
        const int c = t;
        float v = 0.f;
        #pragma unroll 16
        for (int k = 0; k < 64; ++k)
            v = fmaf(sv[k], w_in[(k * 8 + n) * 256 + c], v);
        int R = row >> 4, s = c >> 5, i = c & 7;
        int l = (row & 15) + 16 * ((c >> 3) & 3);
        Aswz[(((R * 8 + s) * 64 + l) << 3) + i] = (_Float16)v;
        if (t < 64) red[t] = sv[t] * b_in[t * 8 + n];
        __syncthreads();
        if (t == 0) {
            float s2 = 0.f;
            for (int k = 0; k < 64; ++k) s2 += red[k];
            bb[row] = s2;
        }
    } else {
        const int o = blk - 512;
        sv[t]       = w_out[o * 512 + t];
        sv[256 + t] = w_out[o * 512 + 256 + t];
        __syncthreads();
        #pragma unroll
        for (int hh = 0; hh < 2; ++hh) {
            int col = t + hh * 256, n = col >> 6, m = col & 63;
            const float4* mrow = (const float4*)(memory + n * 4096 + m * 64);
            const float4* wrow = (const float4*)(sv + n * 64);
            float v = 0.f;
            #pragma unroll
            for (int qd = 0; qd < 16; ++qd) {
                float4 a = mrow[qd], w = wrow[qd];
                v += a.x * w.x + a.y * w.y + a.z * w.z + a.w * w.w;
            }
            int R2 = o >> 4, s = col >> 5, i = col & 7;
            int l = (o & 15) + 16 * ((col >> 3) & 3);
            Mswz[(((R2 * 16 + s) * 64 + l) << 3) + i] = (_Float16)v;
        }
    }
}

// ---------------- main fused kernel ----------------
// 512 WGs x 256 threads; each WG: 64 positions.
// LDS: 64 KB. Phase 1: Xs[p][c] fp16, stride 264 (aliased). Phase 2: P in B-fragment layout.
#define XS_STRIDE 264

__global__ __launch_bounds__(256, 2) void fused_main(
    const float* __restrict__ x, const _Float16* __restrict__ Aswz,
    const float* __restrict__ bb, const _Float16* __restrict__ Mswz,
    const float* __restrict__ b_out, float* __restrict__ out)
{
    __shared__ _Float16 S[32768];   // 64 KB

    const int t  = threadIdx.x;
    const int w  = t >> 6;          // wave 0..3
    const int l  = t & 63;          // lane
    const int q  = l >> 4;          // quadrant 0..3
    const int lp = l & 15;
    const int wg  = blockIdx.x;
    const int b   = wg >> 6;
    const int hw0 = (wg & 63) * 64;
    const float* xb = x + (size_t)b * 256 * 4096 + hw0;

    // ---- stage Xs[p][c] fp16 (transposed), position-fast mapping for coalesced global reads ----
    // lane: qq = t&15 (fast) -> 16 consecutive float4 per row; cp = channel pair (slow)
    #pragma unroll
    for (int i = 0; i < 8; ++i) {
        int u  = i * 256 + t;
        int qq = u & 15;            // position quad 0..15
        int cp = u >> 4;            // channel pair 0..127
        int c0 = cp * 2, p4 = qq * 4;
        const float* px = xb + (size_t)c0 * 4096 + p4;
        float4 v0 = *(const float4*)(px);
        float4 v1 = *(const float4*)(px + 4096);
        *(half2v*)(&S[(p4 + 0) * XS_STRIDE + c0]) = half2v{(_Float16)v0.x, (_Float16)v1.x};
        *(half2v*)(&S[(p4 + 1) * XS_STRIDE + c0]) = half2v{(_Float16)v0.y, (_Float16)v1.y};
        *(half2v*)(&S[(p4 + 2) * XS_STRIDE + c0]) = half2v{(_Float16)v0.z, (_Float16)v1.z};
        *(half2v*)(&S[(p4 + 3) * XS_STRIDE + c0]) = half2v{(_Float16)v0.w, (_Float16)v1.w};
    }

    // ---- pre-issue GEMM1 A-fragments for s=0 (L2 latency hidden under staging/barrier) ----
    const half8* Ag = (const half8*)Aswz;
    half8 af[8];
    #pragma unroll
    for (int r = 0; r < 8; ++r)
        af[r] = Ag[((w * 8 + r) * 8 + 0) * 64 + l];

    __syncthreads();

    // ---- GEMM1: logits[512 x 64], software-pipelined A loads ----
    float4v acc[8][4];
    #pragma unroll
    for (int r = 0; r < 8; ++r)
        #pragma unroll
        for (int c = 0; c < 4; ++c) acc[r][c] = float4v{0.f, 0.f, 0.f, 0.f};

    #pragma unroll
    for (int s = 0; s < 8; ++s) {
        half8 afn[8];
        if (s < 7) {
            #pragma unroll
            for (int r = 0; r < 8; ++r)
                afn[r] = Ag[((w * 8 + r) * 8 + s + 1) * 64 + l];
        }
        half8 bf[4];
        #pragma unroll
        for (int c = 0; c < 4; ++c)
            bf[c] = *(const half8*)(&S[(c * 16 + lp) * XS_STRIDE + s * 32 + q * 8]);
        #pragma unroll
        for (int r = 0; r < 8; ++r)
            #pragma unroll
            for (int c = 0; c < 4; ++c)
                acc[r][c] = __builtin_amdgcn_mfma_f32_16x16x32_f16(af[r], bf[c], acc[r][c], 0, 0, 0);
        if (s < 7) {
            #pragma unroll
            for (int r = 0; r < 8; ++r) af[r] = afn[r];
        }
    }

    // ---- bias ----
    #pragma unroll
    for (int r = 0; r < 8; ++r) {
        float4v bbv = *(const float4v*)(bb + w * 128 + r * 16 + q * 4);
        #pragma unroll
        for (int c = 0; c < 4; ++c)
            #pragma unroll
            for (int j = 0; j < 4; ++j) acc[r][c][j] += bbv[j];
    }

    __syncthreads();   // all waves done reading Xs (P region aliases it)

    // ---- softmax + store P in B-fragment layout ----
    #pragma unroll
    for (int h = 0; h < 2; ++h) {
        #pragma unroll
        for (int c = 0; c < 4; ++c) {
            float mx = -1e30f;
            #pragma unroll
            for (int rr = 0; rr < 4; ++rr) {
                int r = h * 4 + rr;
                #pragma unroll
                for (int j = 0; j < 4; ++j) mx = fmaxf(mx, acc[r][c][j]);
            }
            mx = fmaxf(mx, __shfl_xor(mx, 16, 64));
            mx = fmaxf(mx, __shfl_xor(mx, 32, 64));
            float sum = 0.f;
            #pragma unroll
            for (int rr = 0; rr < 4; ++rr) {
                int r = h * 4 + rr;
                #pragma unroll
                for (int j = 0; j < 4; ++j) {
                    float e = __expf(acc[r][c][j] - mx);
                    acc[r][c][j] = e;
                    sum += e;
                }
            }
            sum += __shfl_xor(sum, 16, 64);
            sum += __shfl_xor(sum, 32, 64);
            float inv = 1.f / sum;
            #pragma unroll
            for (int rr = 0; rr < 4; ++rr) {
                int r = h * 4 + rr;
                int s2 = w * 4 + (r >> 1);
                int lq = ((r & 1) * 2 + (q >> 1)) * 16 + lp;
                int i0 = (q & 1) * 4;
                half4 pv = {(_Float16)(acc[r][c][0] * inv), (_Float16)(acc[r][c][1] * inv),
                            (_Float16)(acc[r][c][2] * inv), (_Float16)(acc[r][c][3] * inv)};
                *(half4*)(&S[(((s2 * 4 + c) * 64) + lq) * 8 + i0]) = pv;
            }
        }
    }

    // ---- pre-issue GEMM2 M-fragments for s2=0 (independent of the barrier) ----
    const half8* Mg = (const half8*)Mswz;
    half8 af2[4];
    #pragma unroll
    for (int r = 0; r < 4; ++r)
        af2[r] = Mg[((w * 4 + r) * 16 + 0) * 64 + l];

    __syncthreads();

    // ---- GEMM2: out[256 x 64] = M[256x512] @ P, software-pipelined ----
    float4v acc2[4][4];
    #pragma unroll
    for (int r = 0; r < 4; ++r)
        #pragma unroll
        for (int c = 0; c < 4; ++c) acc2[r][c] = float4v{0.f, 0.f, 0.f, 0.f};

    #pragma unroll
    for (int s2 = 0; s2 < 16; ++s2) {
        half8 af2n[4];
        if (s2 < 15) {
            #pragma unroll
            for (int r = 0; r < 4; ++r)
                af2n[r] = Mg[((w * 4 + r) * 16 + s2 + 1) * 64 + l];
        }
        half8 bf2[4];
        #pragma unroll
        for (int c = 0; c < 4; ++c)
            bf2[c] = *(const half8*)(&S[(((s2 * 4 + c) * 64) + l) * 8]);   // conflict-free b128
        #pragma unroll
        for (int r = 0; r < 4; ++r)
            #pragma unroll
            for (int c = 0; c < 4; ++c)
                acc2[r][c] = __builtin_amdgcn_mfma_f32_16x16x32_f16(af2[r], bf2[c], acc2[r][c], 0, 0, 0);
        if (s2 < 15) {
            #pragma unroll
            for (int r = 0; r < 4; ++r) af2[r] = af2n[r];
        }
    }

    // ---- epilogue ----
    #pragma unroll
    for (int r = 0; r < 4; ++r) {
        int ob = w * 64 + r * 16 + q * 4;
        float4v bo = *(const float4v*)(b_out + ob);
        #pragma unroll
        for (int j = 0; j < 4; ++j) {
            float* orow = out + ((size_t)b * 256 + ob + j) * 4096 + hw0;
            #pragma unroll
            for (int c = 0; c < 4; ++c)
                orow[c * 16 + lp] = acc2[r][c][j] + bo[j];
        }
    }
}

extern "C" void kernel_launch(void* const* d_in, const int* in_sizes, int n_in,
                              void* d_out, int out_size, void* d_ws, size_t ws_size,
                              hipStream_t stream) {
    (void)in_sizes; (void)n_in; (void)ws_size; (void)out_size;
    const float* x      = (const float*)d_in[0];
    const float* key_p  = (const float*)d_in[1];
    const float* memory = (const float*)d_in[2];
    const float* w_in   = (const float*)d_in[3];
    const float* b_in   = (const float*)d_in[4];
    const float* w_out  = (const float*)d_in[5];
    const float* b_out  = (const float*)d_in[6];
    float* out = (float*)d_out;

    _Float16* Aswz = (_Float16*)d_ws;                       // 512*256 fp16 = 256 KB
    _Float16* Mswz = Aswz + 512 * 256;                      // 256*512 fp16 = 256 KB
    float*    bb   = (float*)(Mswz + 256 * 512);            // 512 fp32

    fold_all<<<768, 256, 0, stream>>>(key_p, w_in, b_in, w_out, memory, Aswz, Mswz, bb);
    fused_main<<<512, 256, 0, stream>>>(x, Aswz, bb, Mswz, b_out, out);
}

// Round 6
// 120.209 us; speedup vs baseline: 1.3876x; 1.0782x over previous
//
#include <hip/hip_runtime.h>

// B=8, IN=256, HEADS=8, KEY=64, MEM=64, HEAD_DIM=64, OUT=256, HW=4096
// Folded form (two kernels; kernel boundary provides fold->main coherence):
//   A[(n,m)][c]  = sum_k key_p[n][k][m] * w_in[k*8+n][c]   (+ bb from b_in)
//   M[o][(n,m)]  = sum_d w_out[o][n*64+d] * memory[n][m][d]
//   logits = A @ x + bb -> softmax(64-row groups) -> out = M @ probs + b_out

typedef _Float16 half8 __attribute__((ext_vector_type(8)));
typedef _Float16 half4 __attribute__((ext_vector_type(4)));
typedef _Float16 half2v __attribute__((ext_vector_type(2)));
typedef float float4v __attribute__((ext_vector_type(4)));

// ---------------- merged fold kernel ----------------
// blocks 0..511: A row (n*64+m); blocks 512..767: M row (o)
__global__ __launch_bounds__(256) void fold_all(
    const float* __restrict__ key_p, const float* __restrict__ w_in,
    const float* __restrict__ b_in, const float* __restrict__ w_out,
    const float* __restrict__ memory,
    _Float16* __restrict__ Aswz, _Float16* __restrict__ Mswz, float* __restrict__ bb)
{
    __shared__ float sv[512];
    __shared__ float red[64];
    const int blk = blockIdx.x;
    const int t = threadIdx.x;

    if (blk < 512) {
        const int row = blk, n = row >> 6, m = row & 63;
        if (t < 64) sv[t] = key_p[n * 4096 + t * 64 + m];   // key column
        __syncthreads();
        const int c = t;
        float v = 0.f;
        #pragma unroll 16
        for (int k = 0; k < 64; ++k)
            v = fmaf(sv[k], w_in[(k * 8 + n) * 256 + c], v);
        int R = row >> 4, s = c >> 5, i = c & 7;
        int l = (row & 15) + 16 * ((c >> 3) & 3);
        Aswz[(((R * 8 + s) * 64 + l) << 3) + i] = (_Float16)v;
        if (t < 64) red[t] = sv[t] * b_in[t * 8 + n];
        __syncthreads();
        if (t == 0) {
            float s2 = 0.f;
            for (int k = 0; k < 64; ++k) s2 += red[k];
            bb[row] = s2;
        }
    } else {
        const int o = blk - 512;
        sv[t]       = w_out[o * 512 + t];
        sv[256 + t] = w_out[o * 512 + 256 + t];
        __syncthreads();
        #pragma unroll
        for (int hh = 0; hh < 2; ++hh) {
            int col = t + hh * 256, n = col >> 6, m = col & 63;
            const float4* mrow = (const float4*)(memory + n * 4096 + m * 64);
            const float4* wrow = (const float4*)(sv + n * 64);
            float v = 0.f;
            #pragma unroll
            for (int qd = 0; qd < 16; ++qd) {
                float4 a = mrow[qd], w = wrow[qd];
                v += a.x * w.x + a.y * w.y + a.z * w.z + a.w * w.w;
            }
            int R2 = o >> 4, s = col >> 5, i = col & 7;
            int l = (o & 15) + 16 * ((col >> 3) & 3);
            Mswz[(((R2 * 16 + s) * 64 + l) << 3) + i] = (_Float16)v;
        }
    }
}

// ---------------- main fused kernel ----------------
// 512 WGs x 256 threads; each WG: 64 positions.
// LDS: 64 KB. Phase 1: Xs[p][c] fp16, stride 264 (aliased). Phase 2: P in B-fragment layout.
// Phase 3 (epilogue): fp32 transpose buffer, stride 68 dwords, two passes of 128 rows.
#define XS_STRIDE 264

__global__ __launch_bounds__(256, 2) void fused_main(
    const float* __restrict__ x, const _Float16* __restrict__ Aswz,
    const float* __restrict__ bb, const _Float16* __restrict__ Mswz,
    const float* __restrict__ b_out, float* __restrict__ out)
{
    __shared__ _Float16 S[32768];   // 64 KB

    const int t  = threadIdx.x;
    const int w  = t >> 6;          // wave 0..3
    const int l  = t & 63;          // lane
    const int q  = l >> 4;          // quadrant 0..3
    const int lp = l & 15;
    const int wg  = blockIdx.x;
    const int b   = wg >> 6;
    const int hw0 = (wg & 63) * 64;
    const float* xb = x + (size_t)b * 256 * 4096 + hw0;

    // ---- stage Xs[p][c] fp16 (transposed); scatter reads absorbed by L3, LDS writes 2-way max ----
    #pragma unroll
    for (int i = 0; i < 8; ++i) {
        int u  = i * 256 + t;
        int cp = u & 127;           // channel pair (lane-fast)
        int qq = u >> 7;            // position quad 0..15
        int c0 = cp * 2, p4 = qq * 4;
        const float* px = xb + (size_t)c0 * 4096 + p4;
        float4 v0 = *(const float4*)(px);
        float4 v1 = *(const float4*)(px + 4096);
        *(half2v*)(&S[(p4 + 0) * XS_STRIDE + c0]) = half2v{(_Float16)v0.x, (_Float16)v1.x};
        *(half2v*)(&S[(p4 + 1) * XS_STRIDE + c0]) = half2v{(_Float16)v0.y, (_Float16)v1.y};
        *(half2v*)(&S[(p4 + 2) * XS_STRIDE + c0]) = half2v{(_Float16)v0.z, (_Float16)v1.z};
        *(half2v*)(&S[(p4 + 3) * XS_STRIDE + c0]) = half2v{(_Float16)v0.w, (_Float16)v1.w};
    }
    __syncthreads();

    // ---- GEMM1: logits[512 x 64] ----
    float4v acc[8][4];
    #pragma unroll
    for (int r = 0; r < 8; ++r)
        #pragma unroll
        for (int c = 0; c < 4; ++c) acc[r][c] = float4v{0.f, 0.f, 0.f, 0.f};

    const half8* Ag = (const half8*)Aswz;
    for (int s = 0; s < 8; ++s) {
        half8 bf[4];
        #pragma unroll
        for (int c = 0; c < 4; ++c)
            bf[c] = *(const half8*)(&S[(c * 16 + lp) * XS_STRIDE + s * 32 + q * 8]);
        half8 af[8];
        #pragma unroll
        for (int r = 0; r < 8; ++r)
            af[r] = Ag[((w * 8 + r) * 8 + s) * 64 + l];
        #pragma unroll
        for (int r = 0; r < 8; ++r)
            #pragma unroll
            for (int c = 0; c < 4; ++c)
                acc[r][c] = __builtin_amdgcn_mfma_f32_16x16x32_f16(af[r], bf[c], acc[r][c], 0, 0, 0);
    }

    // ---- bias ----
    #pragma unroll
    for (int r = 0; r < 8; ++r) {
        float4v bbv = *(const float4v*)(bb + w * 128 + r * 16 + q * 4);
        #pragma unroll
        for (int c = 0; c < 4; ++c)
            #pragma unroll
            for (int j = 0; j < 4; ++j) acc[r][c][j] += bbv[j];
    }

    __syncthreads();   // all waves done reading Xs (P region aliases it)

    // ---- softmax + store P in B-fragment layout ----
    #pragma unroll
    for (int h = 0; h < 2; ++h) {
        #pragma unroll
        for (int c = 0; c < 4; ++c) {
            float mx = -1e30f;
            #pragma unroll
            for (int rr = 0; rr < 4; ++rr) {
                int r = h * 4 + rr;
                #pragma unroll
                for (int j = 0; j < 4; ++j) mx = fmaxf(mx, acc[r][c][j]);
            }
            mx = fmaxf(mx, __shfl_xor(mx, 16, 64));
            mx = fmaxf(mx, __shfl_xor(mx, 32, 64));
            float sum = 0.f;
            #pragma unroll
            for (int rr = 0; rr < 4; ++rr) {
                int r = h * 4 + rr;
                #pragma unroll
                for (int j = 0; j < 4; ++j) {
                    float e = __expf(acc[r][c][j] - mx);
                    acc[r][c][j] = e;
                    sum += e;
                }
            }
            sum += __shfl_xor(sum, 16, 64);
            sum += __shfl_xor(sum, 32, 64);
            float inv = 1.f / sum;
            #pragma unroll
            for (int rr = 0; rr < 4; ++rr) {
                int r = h * 4 + rr;
                int s2 = w * 4 + (r >> 1);
                int lq = ((r & 1) * 2 + (q >> 1)) * 16 + lp;
                int i0 = (q & 1) * 4;
                half4 pv = {(_Float16)(acc[r][c][0] * inv), (_Float16)(acc[r][c][1] * inv),
                            (_Float16)(acc[r][c][2] * inv), (_Float16)(acc[r][c][3] * inv)};
                *(half4*)(&S[(((s2 * 4 + c) * 64) + lq) * 8 + i0]) = pv;
            }
        }
    }
    __syncthreads();

    // ---- GEMM2: out[256 x 64] = M[256x512] @ P ----
    float4v acc2[4][4];
    #pragma unroll
    for (int r = 0; r < 4; ++r)
        #pragma unroll
        for (int c = 0; c < 4; ++c) acc2[r][c] = float4v{0.f, 0.f, 0.f, 0.f};

    const half8* Mg = (const half8*)Mswz;
    for (int s2 = 0; s2 < 16; ++s2) {
        half8 bf2[4];
        #pragma unroll
        for (int c = 0; c < 4; ++c)
            bf2[c] = *(const half8*)(&S[(((s2 * 4 + c) * 64) + l) * 8]);   // conflict-free b128
        half8 af2[4];
        #pragma unroll
        for (int r = 0; r < 4; ++r)
            af2[r] = Mg[((w * 4 + r) * 16 + s2) * 64 + l];
        #pragma unroll
        for (int r = 0; r < 4; ++r)
            #pragma unroll
            for (int c = 0; c < 4; ++c)
                acc2[r][c] = __builtin_amdgcn_mfma_f32_16x16x32_f16(af2[r], bf2[c], acc2[r][c], 0, 0, 0);
    }

    // ---- epilogue: two-pass LDS transpose -> fully-coalesced float4 stores ----
    // acc2[r][c][j]: out row ob = w*64+r*16+q*4+j, position c*16+lp.
    // Pass p covers rows p*128..p*128+127 (written by waves 2p, 2p+1).
    float* Sf = (float*)S;   // stride 68 dwords: 16B-aligned rows, 2-way write / 0-way read conflicts
    #pragma unroll
    for (int pass = 0; pass < 2; ++pass) {
        __syncthreads();   // prior S reads done (GEMM2 bf2 for pass 0, stores for pass 1)
        if ((w >> 1) == pass) {
            int rbase = (w & 1) * 64;
            #pragma unroll
            for (int r = 0; r < 4; ++r)
                #pragma unroll
                for (int j = 0; j < 4; ++j)
                    #pragma unroll
                    for (int c = 0; c < 4; ++c)
                        Sf[(rbase + r * 16 + q * 4 + j) * 68 + c * 16 + lp] = acc2[r][c][j];
        }
        __syncthreads();
        #pragma unroll
        for (int it = 0; it < 8; ++it) {
            int flat = it * 256 + t;    // 0..2047
            int row  = flat >> 4;       // 0..127 (local)
            int ch   = flat & 15;       // float4 chunk (position/4)
            float4 v = *(const float4*)(&Sf[row * 68 + ch * 4]);
            int o = pass * 128 + row;
            float bo = b_out[o];
            v.x += bo; v.y += bo; v.z += bo; v.w += bo;
            *(float4*)(out + ((size_t)b * 256 + o) * 4096 + hw0 + ch * 4) = v;
        }
    }
}

extern "C" void kernel_launch(void* const* d_in, const int* in_sizes, int n_in,
                              void* d_out, int out_size, void* d_ws, size_t ws_size,
                              hipStream_t stream) {
    (void)in_sizes; (void)n_in; (void)ws_size; (void)out_size;
    const float* x      = (const float*)d_in[0];
    const float* key_p  = (const float*)d_in[1];
    const float* memory = (const float*)d_in[2];
    const float* w_in   = (const float*)d_in[3];
    const float* b_in   = (const float*)d_in[4];
    const float* w_out  = (const float*)d_in[5];
    const float* b_out  = (const float*)d_in[6];
    float* out = (float*)d_out;

    _Float16* Aswz = (_Float16*)d_ws;                       // 512*256 fp16 = 256 KB
    _Float16* Mswz = Aswz + 512 * 256;                      // 256*512 fp16 = 256 KB
    float*    bb   = (float*)(Mswz + 256 * 512);            // 512 fp32

    fold_all<<<768, 256, 0, stream>>>(key_p, w_in, b_in, w_out, memory, Aswz, Mswz, bb);
    fused_main<<<512, 256, 0, stream>>>(x, Aswz, bb, Mswz, b_out, out);
}